// Round 1
// baseline (630.961 us; speedup 1.0000x reference)
//
#include <hip/hip_runtime.h>
#include <hip/hip_bf16.h>
#include <math.h>

#define N_NODES 20000
#define N_EDGES 320000
#define EPS_F   1e-6f
#define INV_SD  0.25f          // 1/sqrt(E/N) = 1/4 exactly
#define C0_F    0.28209479177387814f
#define C1_F    0.4886025119029199f
#define C2A_F   1.0925484305920792f
#define C2B_F   0.31539156525252005f
#define C2C_F   0.5462742152960396f

// ---------------- h = x @ w_in  (N x 16) ----------------
__global__ __launch_bounds__(256) void k_h(const float* __restrict__ x,
                                           const float* __restrict__ w_in,
                                           float* __restrict__ h) {
    int n = blockIdx.x * 256 + threadIdx.x;
    if (n >= N_NODES) return;
    float xv[16];
    const float4* px = (const float4*)(x + n * 16);
#pragma unroll
    for (int q = 0; q < 4; ++q) {
        float4 v = px[q];
        xv[q*4+0] = v.x; xv[q*4+1] = v.y; xv[q*4+2] = v.z; xv[q*4+3] = v.w;
    }
#pragma unroll
    for (int c = 0; c < 16; c += 4) {
        float o0 = 0.f, o1 = 0.f, o2 = 0.f, o3 = 0.f;
#pragma unroll
        for (int i = 0; i < 16; ++i) {
            float xi = xv[i];
            o0 = fmaf(xi, w_in[i*16 + c + 0], o0);
            o1 = fmaf(xi, w_in[i*16 + c + 1], o1);
            o2 = fmaf(xi, w_in[i*16 + c + 2], o2);
            o3 = fmaf(xi, w_in[i*16 + c + 3], o3);
        }
        float4 o = make_float4(o0, o1, o2, o3);
        *(float4*)(h + n*16 + c) = o;
    }
}

// ---------------- histogram of dst ----------------
__global__ __launch_bounds__(256) void k_hist(const int* __restrict__ ei,
                                              int* __restrict__ counts) {
    int e = blockIdx.x * 256 + threadIdx.x;
    if (e < N_EDGES) atomicAdd(&counts[ei[N_EDGES + e]], 1);
}

// ---------------- exclusive scan (single block) ----------------
__global__ __launch_bounds__(1024) void k_scan(const int* __restrict__ counts,
                                               int* __restrict__ offsets,
                                               int* __restrict__ cursor) {
    __shared__ int s[1024];
    const int CH = 20;                 // 1024*20 = 20480 >= 20000
    int t = threadIdx.x;
    int base = t * CH;
    int loc[CH];
    int sum = 0;
#pragma unroll
    for (int i = 0; i < CH; ++i) {
        int n = base + i;
        int v = (n < N_NODES) ? counts[n] : 0;
        loc[i] = v; sum += v;
    }
    s[t] = sum;
    __syncthreads();
    for (int off = 1; off < 1024; off <<= 1) {
        int v = (t >= off) ? s[t - off] : 0;
        __syncthreads();
        s[t] += v;
        __syncthreads();
    }
    int run = (t > 0) ? s[t - 1] : 0;
#pragma unroll
    for (int i = 0; i < CH; ++i) {
        int n = base + i;
        if (n < N_NODES) { offsets[n] = run; cursor[n] = run; run += loc[i]; }
    }
    if (t == 1023) offsets[N_NODES] = s[1023];
}

// ---------------- fill CSR edge-id list ----------------
__global__ __launch_bounds__(256) void k_fill(const int* __restrict__ ei,
                                              int* __restrict__ cursor,
                                              int* __restrict__ eidl) {
    int e = blockIdx.x * 256 + threadIdx.x;
    if (e < N_EDGES) {
        int slot = atomicAdd(&cursor[ei[N_EDGES + e]], 1);
        eidl[slot] = e;
    }
}

// ---------------- main: node-centric gather + bilinear ----------------
// block = 256 threads = 16 nodes x 16 channel-lanes
__global__ __launch_bounds__(256) void k_main(
    const int* __restrict__ eidl, const int* __restrict__ offsets,
    const int* __restrict__ ei, const float* __restrict__ eattr,
    const float* __restrict__ h,
    const float* __restrict__ rw1_0, const float* __restrict__ rb1_0,
    const float* __restrict__ rw2_0, const float* __restrict__ rb2_0,
    const float* __restrict__ rw1_1, const float* __restrict__ rb1_1,
    const float* __restrict__ rw2_1, const float* __restrict__ rb2_1,
    const float* __restrict__ rw1_2, const float* __restrict__ rb1_2,
    const float* __restrict__ rw2_2, const float* __restrict__ rb2_2,
    float* __restrict__ out_pre, float* __restrict__ sumsq) {
    // 33 rows of (16 o) x padded-20 floats: rw2 rows j=0..31, rb2 as row 32 (hr=1)
    __shared__ float lds_w[33 * 16 * 20];
    __shared__ float s_sq[48];

    const int tid  = threadIdx.x;
    const int c    = tid & 15;
    const int node = blockIdx.x * 16 + (tid >> 4);
    if (tid < 48) s_sq[tid] = 0.f;

    const float* rw1s[3] = {rw1_0, rw1_1, rw1_2};
    const float* rb1s[3] = {rb1_0, rb1_1, rb1_2};
    const float* rw2s[3] = {rw2_0, rw2_1, rw2_2};
    const float* rb2s[3] = {rb2_0, rb2_1, rb2_2};

    const int off0 = offsets[node];
    const int off1 = offsets[node + 1];

#pragma unroll 1
    for (int l = 0; l < 3; ++l) {
        __syncthreads();   // protect LDS from previous layer's readers
        {
            const float* rw2 = rw2s[l];
            const float* rb2 = rb2s[l];
            for (int r = tid; r < 33 * 16; r += 256) {
                int j = r >> 4, o = r & 15;
                const float* src = (j < 32) ? (rw2 + (j * 16 + o) * 16) : (rb2 + o * 16);
                float* dst = &lds_w[r * 20];
#pragma unroll
                for (int i = 0; i < 16; i += 4) {
                    float4 v = *(const float4*)(src + i);
                    dst[i+0] = v.x; dst[i+1] = v.y; dst[i+2] = v.z; dst[i+3] = v.w;
                }
            }
        }
        __syncthreads();
        const float* rw1 = rw1s[l];
        const float* rb1 = rb1s[l];

        float acc0 = 0.f, acc1 = 0.f, acc2 = 0.f, acc3 = 0.f, acc4 = 0.f;

        for (int k = off0; k < off1; k += 2) {
            int  ea_id = eidl[k];
            bool hasB  = (k + 1 < off1);
            int  eb_id = hasB ? eidl[k + 1] : ea_id;
            int  sa = ei[ea_id];
            int  sb = ei[eb_id];
            float ax = eattr[ea_id*3+0], ay = eattr[ea_id*3+1], az = eattr[ea_id*3+2];
            float bx = 0.f, by = 0.f, bz = 0.f;
            if (hasB) { bx = eattr[eb_id*3+0]; by = eattr[eb_id*3+1]; bz = eattr[eb_id*3+2]; }
            float da = sqrtf(ax*ax + ay*ay + az*az);
            float db = sqrtf(bx*bx + by*by + bz*bz);

            float hsa[16], hsb[16];
            const float4* pa = (const float4*)(h + sa * 16);
            const float4* pb = (const float4*)(h + sb * 16);
#pragma unroll
            for (int q = 0; q < 4; ++q) {
                float4 va = pa[q];
                hsa[q*4+0] = va.x; hsa[q*4+1] = va.y; hsa[q*4+2] = va.z; hsa[q*4+3] = va.w;
                float4 vb = pb[q];
                hsb[q*4+0] = hasB ? vb.x : 0.f;
                hsb[q*4+1] = hasB ? vb.y : 0.f;
                hsb[q*4+2] = hasB ? vb.z : 0.f;
                hsb[q*4+3] = hasB ? vb.w : 0.f;
            }

            // bias row (j==32, hr == 1)
            float m_a, m_b;
            {
                const float* row = &lds_w[(32 * 16 + c) * 20];
                float ta = 0.f, tb = 0.f;
#pragma unroll
                for (int i = 0; i < 16; i += 4) {
                    float4 w4 = *(const float4*)(row + i);
                    ta = fmaf(w4.x, hsa[i+0], ta); ta = fmaf(w4.y, hsa[i+1], ta);
                    ta = fmaf(w4.z, hsa[i+2], ta); ta = fmaf(w4.w, hsa[i+3], ta);
                    tb = fmaf(w4.x, hsb[i+0], tb); tb = fmaf(w4.y, hsb[i+1], tb);
                    tb = fmaf(w4.z, hsb[i+2], tb); tb = fmaf(w4.w, hsb[i+3], tb);
                }
                m_a = ta; m_b = tb;
            }
#pragma unroll 4
            for (int j = 0; j < 32; ++j) {
                float w1  = rw1[j], b1v = rb1[j];
                float hra = fmaxf(fmaf(da, w1, b1v), 0.f);
                float hrb = fmaxf(fmaf(db, w1, b1v), 0.f);
                const float* row = &lds_w[(j * 16 + c) * 20];
                float ta = 0.f, tb = 0.f;
#pragma unroll
                for (int i = 0; i < 16; i += 4) {
                    float4 w4 = *(const float4*)(row + i);
                    ta = fmaf(w4.x, hsa[i+0], ta); ta = fmaf(w4.y, hsa[i+1], ta);
                    ta = fmaf(w4.z, hsa[i+2], ta); ta = fmaf(w4.w, hsa[i+3], ta);
                    tb = fmaf(w4.x, hsb[i+0], tb); tb = fmaf(w4.y, hsb[i+1], tb);
                    tb = fmaf(w4.z, hsb[i+2], tb); tb = fmaf(w4.w, hsb[i+3], tb);
                }
                m_a = fmaf(hra, ta, m_a);
                m_b = fmaf(hrb, tb, m_b);
            }

            if (l == 0) {
                acc0 += m_a + m_b;
            } else {
                float ia = 1.f / (da + EPS_F), ib = 1.f / (db + EPS_F);
                float uax = ax*ia, uay = ay*ia, uaz = az*ia;
                float ubx = bx*ib, uby = by*ib, ubz = bz*ib;
                if (l == 1) {
                    acc0 += C1_F * (m_a*uax + m_b*ubx);
                    acc1 += C1_F * (m_a*uay + m_b*uby);
                    acc2 += C1_F * (m_a*uaz + m_b*ubz);
                } else {
                    acc0 += C2A_F * (m_a*uax*uay + m_b*ubx*uby);
                    acc1 += C2A_F * (m_a*uay*uaz + m_b*uby*ubz);
                    acc2 += C2B_F * (m_a*(3.f*uaz*uaz - 1.f) + m_b*(3.f*ubz*ubz - 1.f));
                    acc3 += C2A_F * (m_a*uax*uaz + m_b*ubx*ubz);
                    acc4 += C2C_F * (m_a*(uax*uax - uay*uay) + m_b*(ubx*ubx - uby*uby));
                }
            }
        }

        float sq;
        if (l == 0) {
            float t0 = acc0 * C0_F * INV_SD;
            out_pre[node * 144 + c] = t0;
            sq = t0 * t0;
        } else if (l == 1) {
            float t0 = acc0 * INV_SD, t1 = acc1 * INV_SD, t2 = acc2 * INV_SD;
            float* p = out_pre + node * 144 + 16 + c * 3;
            p[0] = t0; p[1] = t1; p[2] = t2;
            sq = t0*t0 + t1*t1 + t2*t2;
        } else {
            float t0 = acc0 * INV_SD, t1 = acc1 * INV_SD, t2 = acc2 * INV_SD,
                  t3 = acc3 * INV_SD, t4 = acc4 * INV_SD;
            float* p = out_pre + node * 144 + 64 + c * 5;
            p[0] = t0; p[1] = t1; p[2] = t2; p[3] = t3; p[4] = t4;
            sq = t0*t0 + t1*t1 + t2*t2 + t3*t3 + t4*t4;
        }
        atomicAdd(&s_sq[l * 16 + c], sq);
    }

    __syncthreads();
    if (tid < 48) atomicAdd(&sumsq[tid], s_sq[tid]);
}

// ---------------- finalize: field-norm, w_out mix, relu / gate ----------------
__global__ __launch_bounds__(256) void k_final(
    const float* __restrict__ pre, const float* __restrict__ sumsq,
    const float* __restrict__ w_out0, const float* __restrict__ w_out1,
    const float* __restrict__ w_out2,
    const float* __restrict__ b0, const float* __restrict__ b1,
    const float* __restrict__ b2, float* __restrict__ out) {
    __shared__ float s_inv[48];
    int tid = threadIdx.x;
    if (tid < 48)
        s_inv[tid] = 1.f / (sqrtf(sumsq[tid] * (1.f / (float)N_NODES)) + EPS_F);
    __syncthreads();
    int node = blockIdx.x * 256 + tid;
    if (node >= N_NODES) return;
    const float* t = pre + node * 144;

    // l = 0
    for (int d = 0; d < 16; ++d) {
        float o0 = 0.f;
#pragma unroll
        for (int cc = 0; cc < 16; ++cc)
            o0 = fmaf(t[cc] * s_inv[cc], w_out0[cc * 16 + d], o0);
        out[node * 16 + d] = fmaxf(o0 + b0[d], 0.f);
    }
    // l = 1
    for (int d = 0; d < 16; ++d) {
        float o0 = 0.f, o1 = 0.f, o2 = 0.f;
#pragma unroll
        for (int cc = 0; cc < 16; ++cc) {
            float s = s_inv[16 + cc], w = w_out1[cc * 16 + d];
            const float* tp = t + 16 + cc * 3;
            o0 = fmaf(tp[0] * s, w, o0);
            o1 = fmaf(tp[1] * s, w, o1);
            o2 = fmaf(tp[2] * s, w, o2);
        }
        float nrm = sqrtf(o0*o0 + o1*o1 + o2*o2);
        float g = 1.f / (1.f + expf(-(nrm + b1[d])));
        float* po = out + 320000 + node * 48 + d * 3;
        po[0] = o0 * g; po[1] = o1 * g; po[2] = o2 * g;
    }
    // l = 2
    for (int d = 0; d < 16; ++d) {
        float o0 = 0.f, o1 = 0.f, o2 = 0.f, o3 = 0.f, o4 = 0.f;
#pragma unroll
        for (int cc = 0; cc < 16; ++cc) {
            float s = s_inv[32 + cc], w = w_out2[cc * 16 + d];
            const float* tp = t + 64 + cc * 5;
            o0 = fmaf(tp[0] * s, w, o0);
            o1 = fmaf(tp[1] * s, w, o1);
            o2 = fmaf(tp[2] * s, w, o2);
            o3 = fmaf(tp[3] * s, w, o3);
            o4 = fmaf(tp[4] * s, w, o4);
        }
        float nrm = sqrtf(o0*o0 + o1*o1 + o2*o2 + o3*o3 + o4*o4);
        float g = 1.f / (1.f + expf(-(nrm + b2[d])));
        float* po = out + 1280000 + node * 80 + d * 5;
        po[0] = o0 * g; po[1] = o1 * g; po[2] = o2 * g; po[3] = o3 * g; po[4] = o4 * g;
    }
}

extern "C" void kernel_launch(void* const* d_in, const int* in_sizes, int n_in,
                              void* d_out, int out_size, void* d_ws, size_t ws_size,
                              hipStream_t stream) {
    const float* x     = (const float*)d_in[0];
    const int*   ei    = (const int*)d_in[1];
    const float* eattr = (const float*)d_in[2];
    const float* w_in  = (const float*)d_in[3];
    const float* rw1_0 = (const float*)d_in[4];
    const float* rb1_0 = (const float*)d_in[5];
    const float* rw2_0 = (const float*)d_in[6];
    const float* rb2_0 = (const float*)d_in[7];
    const float* rw1_1 = (const float*)d_in[8];
    const float* rb1_1 = (const float*)d_in[9];
    const float* rw2_1 = (const float*)d_in[10];
    const float* rb2_1 = (const float*)d_in[11];
    const float* rw1_2 = (const float*)d_in[12];
    const float* rb1_2 = (const float*)d_in[13];
    const float* rw2_2 = (const float*)d_in[14];
    const float* rb2_2 = (const float*)d_in[15];
    const float* w_out0 = (const float*)d_in[16];
    const float* b_nl0  = (const float*)d_in[17];
    const float* w_out1 = (const float*)d_in[18];
    const float* b_nl1  = (const float*)d_in[19];
    const float* w_out2 = (const float*)d_in[20];
    const float* b_nl2  = (const float*)d_in[21];
    float* out = (float*)d_out;

    char* ws = (char*)d_ws;
    float* h      = (float*)(ws + 0);          //  320000 f -> ends 1,280,000
    int*   counts = (int*)(ws + 1280000);      //   20000 i -> ends 1,360,000
    int*   offs   = (int*)(ws + 1360128);      //   20001 i -> ends 1,440,132
    int*   cursor = (int*)(ws + 1440384);      //   20000 i -> ends 1,520,384
    int*   eidl   = (int*)(ws + 1520640);      //  320000 i -> ends 2,800,640
    float* pre    = (float*)(ws + 2800640);    // 2,880,000 f -> ends 14,320,640
    float* sumsq  = (float*)(ws + 14320640);   //      48 f

    hipMemsetAsync(counts, 0, N_NODES * sizeof(int), stream);
    hipMemsetAsync(sumsq, 0, 48 * sizeof(float), stream);

    k_h   <<<(N_NODES + 255) / 256, 256, 0, stream>>>(x, w_in, h);
    k_hist<<<(N_EDGES + 255) / 256, 256, 0, stream>>>(ei, counts);
    k_scan<<<1, 1024, 0, stream>>>(counts, offs, cursor);
    k_fill<<<(N_EDGES + 255) / 256, 256, 0, stream>>>(ei, cursor, eidl);
    k_main<<<N_NODES / 16, 256, 0, stream>>>(
        eidl, offs, ei, eattr, h,
        rw1_0, rb1_0, rw2_0, rb2_0,
        rw1_1, rb1_1, rw2_1, rb2_1,
        rw1_2, rb1_2, rw2_2, rb2_2,
        pre, sumsq);
    k_final<<<(N_NODES + 255) / 256, 256, 0, stream>>>(
        pre, sumsq, w_out0, w_out1, w_out2, b_nl0, b_nl1, b_nl2, out);
}

// Round 3
// 265.847 us; speedup vs baseline: 2.3734x; 2.3734x over previous
//
#include <hip/hip_runtime.h>
#include <hip/hip_bf16.h>
#include <math.h>

#define N_NODES 20000
#define N_EDGES 320000
#define EPS_F   1e-6f
#define INV_SD  0.25f          // 1/sqrt(E/N) = 1/4 exactly
#define C0_F    0.28209479177387814f
#define C1_F    0.4886025119029199f
#define C2A_F   1.0925484305920792f
#define C2B_F   0.31539156525252005f
#define C2C_F   0.5462742152960396f

typedef _Float16 half2v __attribute__((ext_vector_type(2)));
typedef _Float16 half4v __attribute__((ext_vector_type(4)));
typedef _Float16 half8v __attribute__((ext_vector_type(8)));
typedef float    float4v __attribute__((ext_vector_type(4)));

// __builtin_amdgcn_cvt_pkrtz returns __fp16x2; bit-cast to _Float16x2
static __device__ __forceinline__ half2v pkrtz(float a, float b) {
    return __builtin_bit_cast(half2v, __builtin_amdgcn_cvt_pkrtz(a, b));
}

// LDS layout (bytes):
//   [0, 52224)          W fragments: 3 layers x 17 ksteps x 64 lanes x 16B (f16 B-frags)
//   [52224 + wid*2048)  per-wave: hs 16 rows x 48B (32B data + d at +32), then T 16 rows x 80B
//   [60416, 60608)      s_sq[48] float
#define SMEM_BYTES 60608
#define W_FRAGS    3264        // 3*17*64
#define WAVE_OFF   52224
#define SSQ_OFF    60416

// ---------------- h = x @ w_in  (N x 16) ----------------
__global__ __launch_bounds__(256) void k_h(const float* __restrict__ x,
                                           const float* __restrict__ w_in,
                                           float* __restrict__ h) {
    int n = blockIdx.x * 256 + threadIdx.x;
    if (n >= N_NODES) return;
    float xv[16];
    const float4* px = (const float4*)(x + n * 16);
#pragma unroll
    for (int q = 0; q < 4; ++q) {
        float4 v = px[q];
        xv[q*4+0] = v.x; xv[q*4+1] = v.y; xv[q*4+2] = v.z; xv[q*4+3] = v.w;
    }
#pragma unroll
    for (int c = 0; c < 16; c += 4) {
        float o0 = 0.f, o1 = 0.f, o2 = 0.f, o3 = 0.f;
#pragma unroll
        for (int i = 0; i < 16; ++i) {
            float xi = xv[i];
            o0 = fmaf(xi, w_in[i*16 + c + 0], o0);
            o1 = fmaf(xi, w_in[i*16 + c + 1], o1);
            o2 = fmaf(xi, w_in[i*16 + c + 2], o2);
            o3 = fmaf(xi, w_in[i*16 + c + 3], o3);
        }
        float4 o = make_float4(o0, o1, o2, o3);
        *(float4*)(h + n*16 + c) = o;
    }
}

// ---------------- histogram of dst ----------------
__global__ __launch_bounds__(256) void k_hist(const int* __restrict__ ei,
                                              int* __restrict__ counts) {
    int e = blockIdx.x * 256 + threadIdx.x;
    if (e < N_EDGES) atomicAdd(&counts[ei[N_EDGES + e]], 1);
}

// ---------------- exclusive scan (single block) ----------------
__global__ __launch_bounds__(1024) void k_scan(const int* __restrict__ counts,
                                               int* __restrict__ offsets,
                                               int* __restrict__ cursor) {
    __shared__ int s[1024];
    const int CH = 20;                 // 1024*20 = 20480 >= 20000
    int t = threadIdx.x;
    int base = t * CH;
    int loc[CH];
    int sum = 0;
#pragma unroll
    for (int i = 0; i < CH; ++i) {
        int n = base + i;
        int v = (n < N_NODES) ? counts[n] : 0;
        loc[i] = v; sum += v;
    }
    s[t] = sum;
    __syncthreads();
    for (int off = 1; off < 1024; off <<= 1) {
        int v = (t >= off) ? s[t - off] : 0;
        __syncthreads();
        s[t] += v;
        __syncthreads();
    }
    int run = (t > 0) ? s[t - 1] : 0;
#pragma unroll
    for (int i = 0; i < CH; ++i) {
        int n = base + i;
        if (n < N_NODES) { offsets[n] = run; cursor[n] = run; run += loc[i]; }
    }
    if (t == 1023) offsets[N_NODES] = s[1023];
}

// ---------------- fill CSR edge-id list ----------------
__global__ __launch_bounds__(256) void k_fill(const int* __restrict__ ei,
                                              int* __restrict__ cursor,
                                              int* __restrict__ eidl) {
    int e = blockIdx.x * 256 + threadIdx.x;
    if (e < N_EDGES) {
        int slot = atomicAdd(&cursor[ei[N_EDGES + e]], 1);
        eidl[slot] = e;
    }
}

// ---------------- main: node-per-wave, MFMA bilinear + MFMA Y-contraction ----
__global__ __launch_bounds__(256) void k_main(
    const int* __restrict__ eidl, const int* __restrict__ offsets,
    const int* __restrict__ ei, const float* __restrict__ eattr,
    const float* __restrict__ h,
    const float* __restrict__ rw1_0, const float* __restrict__ rb1_0,
    const float* __restrict__ rw2_0, const float* __restrict__ rb2_0,
    const float* __restrict__ rw1_1, const float* __restrict__ rb1_1,
    const float* __restrict__ rw2_1, const float* __restrict__ rb2_1,
    const float* __restrict__ rw1_2, const float* __restrict__ rb1_2,
    const float* __restrict__ rw2_2, const float* __restrict__ rb2_2,
    float* __restrict__ out_pre, float* __restrict__ sumsq) {

    __shared__ __align__(16) char smem[SMEM_BYTES];
    const int tid = threadIdx.x;

    // ---- zero all LDS (avoid NaN garbage reaching MFMA B operands) ----
    {
        float4* z = (float4*)smem;
        for (int i = tid; i < SMEM_BYTES / 16; i += 256) z[i] = make_float4(0.f,0.f,0.f,0.f);
    }
    __syncthreads();

    // ---- stage W fragments (f16), pre-swizzled for 16x16x32 B-operand ----
    {
        const float* rw2s[3] = {rw2_0, rw2_1, rw2_2};
        const float* rb2s[3] = {rb2_0, rb2_1, rb2_2};
        for (int fid = tid; fid < W_FRAGS; fid += 256) {
            int l = fid / 1088, r = fid - l * 1088;
            int s = r >> 6, ln = r & 63, q2 = ln >> 4, oo = ln & 15;
            const float* src;
            if (s < 16)      src = rw2s[l] + (2*s + (q2>>1))*256 + oo*16 + (q2&1)*8;
            else if (q2 < 2) src = rb2s[l] + oo*16 + (q2&1)*8;
            else continue;   // stays zero
            float4 A = *(const float4*)src;
            float4 B = *(const float4*)(src + 4);
            union { half8v v; half2v p[4]; } u;
            u.p[0] = pkrtz(A.x, A.y);
            u.p[1] = pkrtz(A.z, A.w);
            u.p[2] = pkrtz(B.x, B.y);
            u.p[3] = pkrtz(B.z, B.w);
            *(half8v*)(smem + fid * 16) = u.v;
        }
    }
    __syncthreads();

    const int wid  = tid >> 6;
    const int lane = tid & 63;
    const int oidx = lane & 15;        // o for B/m, mu for Y/A, e for A(hs)
    const int q    = lane >> 4;
    const int p    = q >> 1;
    const int te   = lane >> 2;        // edge handled by this setup team
    const int sub  = lane & 3;

    char* hsb = smem + WAVE_OFF + wid * 2048;   // 16 rows x 48B
    char* Tb  = hsb + 768;                      // 16 rows x 80B (Y rows 1..8 / m rows 0..15)
    float* s_sqf = (float*)(smem + SSQ_OFF);

    const float* rw1s[3] = {rw1_0, rw1_1, rw1_2};
    const float* rb1s[3] = {rb1_0, rb1_1, rb1_2};

    // constant layer-0 A fragment: row mu=0 = C0 for e=0..15 (q<2)
    half8v af0 = {};
    if (oidx == 0 && q < 2) {
        _Float16 c0 = (_Float16)C0_F;
        af0 = (half8v){c0,c0,c0,c0,c0,c0,c0,c0};
    }

    float sqa[4] = {0.f, 0.f, 0.f, 0.f};
    const int gwave = blockIdx.x * 4 + wid;

    for (int node = gwave; node < N_NODES; node += 2048) {
        const int off0 = offsets[node];
        const int off1 = offsets[node + 1];

        float4v acc2 = {0.f, 0.f, 0.f, 0.f};

        for (int k0 = off0; k0 < off1; k0 += 16) {
            // ---------- setup: 4 lanes per edge ----------
            int slot = k0 + te;
            bool valid = (slot < off1);
            int cl = valid ? slot : (off1 - 1);
            int eid = eidl[cl];
            int src = ei[eid];
            float ax = eattr[eid*3+0], ay = eattr[eid*3+1], az = eattr[eid*3+2];
            float d = sqrtf(ax*ax + ay*ay + az*az);
            float inv = 1.f / (d + EPS_F);
            float ux = ax*inv, uy = ay*inv, uz = az*inv;

            float4 hv = ((const float4*)h)[src*4 + sub];
            if (!valid) { hv.x = 0.f; hv.y = 0.f; hv.z = 0.f; hv.w = 0.f; }
            {
                union { half4v v; half2v p[2]; } u;
                u.p[0] = pkrtz(hv.x, hv.y);
                u.p[1] = pkrtz(hv.z, hv.w);
                *(half4v*)(hsb + te*48 + sub*8) = u.v;
            }
            if (sub == 0) *(float*)(hsb + te*48 + 32) = d;

            // Y rows 1..8 (f16), 2 rows per sub-lane
            {
                float va = (sub==0) ? C1_F*ux  :
                           (sub==1) ? C1_F*uz  :
                           (sub==2) ? C2A_F*uy*uz : C2A_F*ux*uz;
                float vb = (sub==0) ? C1_F*uy  :
                           (sub==1) ? C2A_F*ux*uy :
                           (sub==2) ? C2B_F*(3.f*uz*uz - 1.f) : C2C_F*(ux*ux - uy*uy);
                int ra = 1 + sub*2, rb = 2 + sub*2;
                *(_Float16*)(Tb + ra*80 + te*2) = (_Float16)va;
                *(_Float16*)(Tb + rb*80 + te*2) = (_Float16)vb;
            }

            // ---------- per-lane reads (same-wave LDS, in-order) ----------
            float d_e = *(const float*)(hsb + oidx*48 + 32);
            half8v hs8 = *(const half8v*)(hsb + oidx*48 + (q & 1) * 16);
            half8v yv  = *(const half8v*)(Tb + oidx*80 + q*16);
            bool in1 = (q < 2) && (oidx >= 1 && oidx <= 3);
            bool in2 = (q < 2) && (oidx >= 4 && oidx <= 8);
            half8v zero8 = {};
            half8v yv1 = in1 ? yv : zero8;
            half8v yv2 = in2 ? yv : zero8;

            // ---------- 3 layers ----------
#pragma unroll
            for (int l = 0; l < 3; ++l) {
                const float* rw1 = rw1s[l];
                const float* rb1 = rb1s[l];
                half2v hrv[17];
#pragma unroll
                for (int s = 0; s < 16; ++s) {
                    float w1 = p ? rw1[2*s+1] : rw1[2*s];
                    float b1 = p ? rb1[2*s+1] : rb1[2*s];
                    float hr = fmaxf(fmaf(d_e, w1, b1), 0.f);
                    hrv[s] = pkrtz(hr, hr);
                }
                hrv[16] = p ? (half2v){} : pkrtz(1.f, 1.f);

                float4v accB = {0.f, 0.f, 0.f, 0.f};
#pragma unroll
                for (int s = 0; s < 17; ++s) {
                    half8v bfr = *(const half8v*)(smem + (l*1088 + s*64 + lane) * 16);
                    half8v hsp = __builtin_shufflevector(hrv[s], hrv[s], 0,1,0,1,0,1,0,1);
                    half8v afr = hs8 * hsp;
                    accB = __builtin_amdgcn_mfma_f32_16x16x32_f16(afr, bfr, accB, 0, 0, 0);
                }

                // m (f16) -> T rows [o][e], then stage-C MFMA
                {
                    union { half4v v; half2v pp[2]; } um;
                    um.pp[0] = pkrtz(accB[0], accB[1]);
                    um.pp[1] = pkrtz(accB[2], accB[3]);
                    *(half4v*)(Tb + oidx*80 + q*8) = um.v;
                }
                half8v bfr2 = *(const half8v*)(Tb + oidx*80 + q*16);
                half8v af = (l == 0) ? af0 : ((l == 1) ? yv1 : yv2);
                acc2 = __builtin_amdgcn_mfma_f32_16x16x32_f16(af, bfr2, acc2, 0, 0, 0);
            }
        }

        // ---------- epilogue: store pre[node], accumulate sq ----------
#pragma unroll
        for (int reg = 0; reg < 4; ++reg) {
            int mu = q*4 + reg;
            float t = acc2[reg] * INV_SD;
            int idx; bool ok = true;
            if (mu == 0)      idx = oidx;
            else if (mu <= 3) idx = 16 + oidx*3 + (mu - 1);
            else if (mu <= 8) idx = 64 + oidx*5 + (mu - 4);
            else ok = false;
            if (ok) {
                out_pre[node*144 + idx] = t;
                sqa[reg] += t * t;
            }
        }
    }

    // ---------- sumsq reduction ----------
#pragma unroll
    for (int reg = 0; reg < 4; ++reg) {
        int mu = q*4 + reg;
        if (mu <= 8) {
            int lsel = (mu == 0) ? 0 : ((mu <= 3) ? 1 : 2);
            atomicAdd(&s_sqf[lsel*16 + oidx], sqa[reg]);
        }
    }
    __syncthreads();
    if (tid < 48) atomicAdd(&sumsq[tid], s_sqf[tid]);
}

// ---------------- finalize: field-norm, w_out mix, relu / gate ----------------
__global__ __launch_bounds__(256) void k_final(
    const float* __restrict__ pre, const float* __restrict__ sumsq,
    const float* __restrict__ w_out0, const float* __restrict__ w_out1,
    const float* __restrict__ w_out2,
    const float* __restrict__ b0, const float* __restrict__ b1,
    const float* __restrict__ b2, float* __restrict__ out) {
    __shared__ float s_inv[48];
    int tid = threadIdx.x;
    if (tid < 48)
        s_inv[tid] = 1.f / (sqrtf(sumsq[tid] * (1.f / (float)N_NODES)) + EPS_F);
    __syncthreads();
    int node = blockIdx.x * 256 + tid;
    if (node >= N_NODES) return;
    const float* t = pre + node * 144;

    // l = 0
    for (int d = 0; d < 16; ++d) {
        float o0 = 0.f;
#pragma unroll
        for (int cc = 0; cc < 16; ++cc)
            o0 = fmaf(t[cc] * s_inv[cc], w_out0[cc * 16 + d], o0);
        out[node * 16 + d] = fmaxf(o0 + b0[d], 0.f);
    }
    // l = 1
    for (int d = 0; d < 16; ++d) {
        float o0 = 0.f, o1 = 0.f, o2 = 0.f;
#pragma unroll
        for (int cc = 0; cc < 16; ++cc) {
            float s = s_inv[16 + cc], w = w_out1[cc * 16 + d];
            const float* tp = t + 16 + cc * 3;
            o0 = fmaf(tp[0] * s, w, o0);
            o1 = fmaf(tp[1] * s, w, o1);
            o2 = fmaf(tp[2] * s, w, o2);
        }
        float nrm = sqrtf(o0*o0 + o1*o1 + o2*o2);
        float g = 1.f / (1.f + expf(-(nrm + b1[d])));
        float* po = out + 320000 + node * 48 + d * 3;
        po[0] = o0 * g; po[1] = o1 * g; po[2] = o2 * g;
    }
    // l = 2
    for (int d = 0; d < 16; ++d) {
        float o0 = 0.f, o1 = 0.f, o2 = 0.f, o3 = 0.f, o4 = 0.f;
#pragma unroll
        for (int cc = 0; cc < 16; ++cc) {
            float s = s_inv[32 + cc], w = w_out2[cc * 16 + d];
            const float* tp = t + 64 + cc * 5;
            o0 = fmaf(tp[0] * s, w, o0);
            o1 = fmaf(tp[1] * s, w, o1);
            o2 = fmaf(tp[2] * s, w, o2);
            o3 = fmaf(tp[3] * s, w, o3);
            o4 = fmaf(tp[4] * s, w, o4);
        }
        float nrm = sqrtf(o0*o0 + o1*o1 + o2*o2 + o3*o3 + o4*o4);
        float g = 1.f / (1.f + expf(-(nrm + b2[d])));
        float* po = out + 1280000 + node * 80 + d * 5;
        po[0] = o0 * g; po[1] = o1 * g; po[2] = o2 * g; po[3] = o3 * g; po[4] = o4 * g;
    }
}

extern "C" void kernel_launch(void* const* d_in, const int* in_sizes, int n_in,
                              void* d_out, int out_size, void* d_ws, size_t ws_size,
                              hipStream_t stream) {
    const float* x     = (const float*)d_in[0];
    const int*   ei    = (const int*)d_in[1];
    const float* eattr = (const float*)d_in[2];
    const float* w_in  = (const float*)d_in[3];
    const float* rw1_0 = (const float*)d_in[4];
    const float* rb1_0 = (const float*)d_in[5];
    const float* rw2_0 = (const float*)d_in[6];
    const float* rb2_0 = (const float*)d_in[7];
    const float* rw1_1 = (const float*)d_in[8];
    const float* rb1_1 = (const float*)d_in[9];
    const float* rw2_1 = (const float*)d_in[10];
    const float* rb2_1 = (const float*)d_in[11];
    const float* rw1_2 = (const float*)d_in[12];
    const float* rb1_2 = (const float*)d_in[13];
    const float* rw2_2 = (const float*)d_in[14];
    const float* rb2_2 = (const float*)d_in[15];
    const float* w_out0 = (const float*)d_in[16];
    const float* b_nl0  = (const float*)d_in[17];
    const float* w_out1 = (const float*)d_in[18];
    const float* b_nl1  = (const float*)d_in[19];
    const float* w_out2 = (const float*)d_in[20];
    const float* b_nl2  = (const float*)d_in[21];
    float* out = (float*)d_out;

    char* ws = (char*)d_ws;
    float* h      = (float*)(ws + 0);          //  320000 f -> ends 1,280,000
    int*   counts = (int*)(ws + 1280000);      //   20000 i -> ends 1,360,000
    int*   offs   = (int*)(ws + 1360128);      //   20001 i -> ends 1,440,132
    int*   cursor = (int*)(ws + 1440384);      //   20000 i -> ends 1,520,384
    int*   eidl   = (int*)(ws + 1520640);      //  320000 i -> ends 2,800,640
    float* pre    = (float*)(ws + 2800640);    // 2,880,000 f -> ends 14,320,640
    float* sumsq  = (float*)(ws + 14320640);   //      48 f

    (void)hipMemsetAsync(counts, 0, N_NODES * sizeof(int), stream);
    (void)hipMemsetAsync(sumsq, 0, 48 * sizeof(float), stream);

    k_h   <<<(N_NODES + 255) / 256, 256, 0, stream>>>(x, w_in, h);
    k_hist<<<(N_EDGES + 255) / 256, 256, 0, stream>>>(ei, counts);
    k_scan<<<1, 1024, 0, stream>>>(counts, offs, cursor);
    k_fill<<<(N_EDGES + 255) / 256, 256, 0, stream>>>(ei, cursor, eidl);
    k_main<<<512, 256, 0, stream>>>(
        eidl, offs, ei, eattr, h,
        rw1_0, rb1_0, rw2_0, rb2_0,
        rw1_1, rb1_1, rw2_1, rb2_1,
        rw1_2, rb1_2, rw2_2, rb2_2,
        pre, sumsq);
    k_final<<<(N_NODES + 255) / 256, 256, 0, stream>>>(
        pre, sumsq, w_out0, w_out1, w_out2, b_nl0, b_nl1, b_nl2, out);
}